// Round 7
// baseline (721.293 us; speedup 1.0000x reference)
//
#include <hip/hip_runtime.h>
#include <hip/hip_bf16.h>

typedef unsigned short u16;
typedef __attribute__((ext_vector_type(8))) short shortx8;
typedef __attribute__((ext_vector_type(4))) float floatx4;

// ---------- helpers ----------
__device__ __forceinline__ float bf2f(u16 u) {
    union { unsigned int ui; float f; } x; x.ui = ((unsigned int)u) << 16; return x.f;
}
__device__ __forceinline__ u16 f2b(float f) {
    union { float f; unsigned int u; } x; x.f = f;
    unsigned int r = (x.u + 0x7fffu + ((x.u >> 16) & 1u)) >> 16;   // RNE
    return (u16)r;
}
__device__ __forceinline__ void glds16(const void* g, void* l) {
    __builtin_amdgcn_global_load_lds((const __attribute__((address_space(1))) void*)g,
                                     (__attribute__((address_space(3))) void*)l, 16, 0, 0);
}

// ---------- fp32 -> bf16 elementwise (encodings) ----------
__global__ __launch_bounds__(256) void cvt_bf16_kernel(const float* __restrict__ src,
                                                       u16* __restrict__ dst, int n) {
    int i = (blockIdx.x * 256 + threadIdx.x) * 4;
    if (i + 3 < n) {
        float4 v = *(const float4*)&src[i];
        ushort4 o; o.x = f2b(v.x); o.y = f2b(v.y); o.z = f2b(v.z); o.w = f2b(v.w);
        *(ushort4*)&dst[i] = o;
    }
}

// ---------- build Bsmall' [1024][512] bf16 via coalesced LDS transpose ----------
__global__ __launch_bounds__(256) void build_bsmall_t(const float* __restrict__ mu,
                                                      const float* __restrict__ sg,
                                                      const float* __restrict__ b1,
                                                      const float* __restrict__ b2,
                                                      u16* __restrict__ Bs) {
    __shared__ float t[32][33];
    const float* src;
    int z = blockIdx.z;
    if (z == 0) src = mu; else if (z == 1) src = sg; else if (z == 2) src = b1; else src = b2;
    int k0 = blockIdx.x * 32, c0 = blockIdx.y * 32;
    int r = threadIdx.x >> 3, c4 = (threadIdx.x & 7) * 4;
    float4 v = *(const float4*)&src[(size_t)(k0 + r) * 256 + c0 + c4];
    t[r][c4] = v.x; t[r][c4 + 1] = v.y; t[r][c4 + 2] = v.z; t[r][c4 + 3] = v.w;
    __syncthreads();
    ushort4 o;
    o.x = f2b(t[c4 + 0][r]); o.y = f2b(t[c4 + 1][r]);
    o.z = f2b(t[c4 + 2][r]); o.w = f2b(t[c4 + 3][r]);
    *(ushort4*)&Bs[(size_t)(z * 256 + c0 + r) * 512 + k0 + c4] = o;
}

// ---------- fc_w fp32 [512][65536] -> bf16 transposed [65536][512] ----------
// 64k x 32n tile.  Writes 16B/thread (shortx8), 128B-contiguous per 8-thread
// run; reads 128B-coalesced; LDS gather at stride 33 is 2-way aliasing (free).
__global__ __launch_bounds__(256) void cvt_transpose(const float* __restrict__ W,
                                                     u16* __restrict__ Bt) {
    __shared__ float t[64][33];
    int n0 = blockIdx.x * 32, k0 = blockIdx.y * 64;
    int r = threadIdx.x >> 2;          // 0..63 (k-row)
    int c = (threadIdx.x & 3) * 8;     // 0,8,16,24 (n-col)
    float4 v0 = *(const float4*)&W[(size_t)(k0 + r) * 65536 + n0 + c];
    float4 v1 = *(const float4*)&W[(size_t)(k0 + r) * 65536 + n0 + c + 4];
    t[r][c + 0] = v0.x; t[r][c + 1] = v0.y; t[r][c + 2] = v0.z; t[r][c + 3] = v0.w;
    t[r][c + 4] = v1.x; t[r][c + 5] = v1.y; t[r][c + 6] = v1.z; t[r][c + 7] = v1.w;
    __syncthreads();
    int nr = threadIdx.x >> 3;         // 0..31 (n-row)
    int kk = (threadIdx.x & 7) * 8;    // 0..56 (k)
    shortx8 o;
    #pragma unroll
    for (int i = 0; i < 8; i++) o[i] = (short)f2b(t[kk + i][nr]);
    *(shortx8*)&Bt[(size_t)(n0 + nr) * 512 + k0 + kk] = o;
}

// ---------- slots + Y1/Y2 bias init (fused; reads P once) ----------
__global__ __launch_bounds__(256) void slots_init(const float* __restrict__ P,
                                                  const float* __restrict__ eps,
                                                  float* __restrict__ slots,
                                                  float* __restrict__ Y1,
                                                  float* __restrict__ Y2) {
    int t = blockIdx.x, d = threadIdx.x;
    float mu = P[(size_t)t * 1024 + d];
    float sg = expf(0.5f * P[(size_t)t * 1024 + 256 + d]);
    float b1 = P[(size_t)t * 1024 + 512 + d];
    float b2 = P[(size_t)t * 1024 + 768 + d];
    Y1[((size_t)t * 2 + 0) * 256 + d] = b1;
    Y1[((size_t)t * 2 + 1) * 256 + d] = b1;
    Y2[((size_t)t * 2 + 0) * 256 + d] = b2;
    Y2[((size_t)t * 2 + 1) * 256 + d] = b2;
    int b = t >> 6, n = t & 63;
    #pragma unroll
    for (int m = 0; m < 2; m++) {
        float e = eps[(size_t)(((b * 2 + m) * 64) + n) * 256 + d];
        slots[(size_t)t * 512 + m * 256 + d] = mu + sg * e;
    }
}

// ---------- small MFMA GEMM (fp32 out): P = Eb * Bsm^T ----------
__global__ __launch_bounds__(256, 2) void gemm_small(const u16* __restrict__ A,
                                                     const u16* __restrict__ B,
                                                     float* __restrict__ C,
                                                     int N, int K,
                                                     int nbx_l2, int bypx_l2) {
    __shared__ __align__(16) u16 As[128 * 64];
    __shared__ __align__(16) u16 Bs[128 * 64];
    int tid = threadIdx.x;
    int wave = tid >> 6, lane = tid & 63;

    int id = blockIdx.x;
    int xcd = id & 7, sq = id >> 3;
    int by = (xcd << bypx_l2) + (sq >> nbx_l2);
    int bx = sq & ((1 << nbx_l2) - 1);
    int m0 = bx * 128, n0 = by * 128;
    int wm = wave >> 1, wn = wave & 1;

    floatx4 acc[4][4];
    #pragma unroll
    for (int r = 0; r < 4; r++)
        #pragma unroll
        for (int c = 0; c < 4; c++)
            #pragma unroll
            for (int q = 0; q < 4; q++) acc[r][c][q] = 0.f;

    int lrsub = lane >> 3, kcl = lane & 7;
    const u16* gA[4]; const u16* gB[4]; u16* lA[4]; u16* lB[4];
    #pragma unroll
    for (int j = 0; j < 4; j++) {
        int r0 = (wave * 4 + j) * 8;
        int row = r0 + lrsub;
        int kof = (kcl ^ (row & 7)) * 8;
        gA[j] = A + (size_t)(m0 + row) * K + kof;
        gB[j] = B + (size_t)(n0 + row) * K + kof;
        lA[j] = As + r0 * 64;
        lB[j] = Bs + r0 * 64;
    }

    int arb = wm * 64 + (lane & 15);
    int brb = wn * 64 + (lane & 15);
    int axr = arb & 7, bxr = brb & 7;
    int cl0 = lane >> 4;

    for (int k0 = 0; k0 < K; k0 += 64) {
        #pragma unroll
        for (int j = 0; j < 4; j++) glds16(gA[j] + k0, lA[j]);
        #pragma unroll
        for (int j = 0; j < 4; j++) glds16(gB[j] + k0, lB[j]);
        __syncthreads();
        #pragma unroll
        for (int s = 0; s < 2; s++) {
            shortx8 af[4], bf[4];
            int ac = ((s * 4 + cl0) ^ axr) * 8;
            int bc = ((s * 4 + cl0) ^ bxr) * 8;
            #pragma unroll
            for (int r = 0; r < 4; r++) af[r] = *(const shortx8*)(As + (arb + r * 16) * 64 + ac);
            #pragma unroll
            for (int c = 0; c < 4; c++) bf[c] = *(const shortx8*)(Bs + (brb + c * 16) * 64 + bc);
            #pragma unroll
            for (int r = 0; r < 4; r++)
                #pragma unroll
                for (int c = 0; c < 4; c++)
                    acc[r][c] = __builtin_amdgcn_mfma_f32_16x16x32_bf16(af[r], bf[c], acc[r][c], 0, 0, 0);
        }
        __syncthreads();
    }

    int crow0 = m0 + wm * 64 + (lane >> 4) * 4;
    int ccol  = n0 + wn * 64 + (lane & 15);
    #pragma unroll
    for (int r = 0; r < 4; r++)
        #pragma unroll
        for (int c = 0; c < 4; c++)
            #pragma unroll
            for (int q = 0; q < 4; q++)
                C[(size_t)(crow0 + r * 16 + q) * N + ccol + c * 16] = acc[r][c][q];
}

// ---------- fused mixture-GEMM + apply ----------
// Block = (token-tile 128, h-tile 64, g-group 32), 512 blocks = 2/CU exact.
// g in PAIRS (G_INNER=2, F=4.0 fragment reuse, round 4).
//
// Round-7 pipeline (fixes round-6's regression): counted-vmcnt with
// B-ONLY double-buffering, sl kept in LDS:
//  - LDS = As 16K + Bs[2][2] 32K + sl 16K = 64KB exact.
//  - per ks step: issue A-cur (4 glds, single-buffered As) -> issue B-next
//    (4 glds into Bs[nb]) -> vmcnt(4) (waits B-cur + A-cur; leaves B-next
//    in flight across compute+barrier+apply) -> barrier -> compute -> barrier.
//  - apply reads sl via LDS (lgkmcnt) => ZERO vmcnt interaction.  Round 6
//    read S from global in the apply; the in-order vmcnt counter then
//    drained the prefetch every gp AND added 64 naked L2 loads (170->209us).
//  - sl layout [t][m][g] (t-major): staging writes are g-contiguous ->
//    conflict-free (round-5's [g][m][t] layout was the 4.06M bank conflicts).
//
// REGISTER ECONOMICS (rounds 0-3): only (256,2) avoids spilling ~200-reg
// live state.  Spill tripwire: FETCH_SIZE must stay ~45-55MB.
__global__ __launch_bounds__(256, 2) void fused_mlp(const u16* __restrict__ Eb,
                                                    const u16* __restrict__ Bt,
                                                    const float* __restrict__ S,
                                                    float* __restrict__ Y,
                                                    int relu_s) {
    __shared__ __align__(16) u16 As[128 * 64];         // 16 KB (single buf)
    __shared__ __align__(16) u16 Bs[2][2][64 * 64];    // 32 KB [buf][g-tile]
    __shared__ float sl[128 * 2 * 16];                 // [t][m][g] 16 KB
    int tid = threadIdx.x;
    int wave = tid >> 6, lane = tid & 63;

    // decode with XCD-affinity on (hh,gg): same-B blocks share an XCD.
    int id = blockIdx.x;
    int xcd = id & 7;
    int rest = id >> 3;
    int tt = rest & 15;              // 0..15
    int chi = rest >> 4;             // 0..3
    int combo = chi * 8 + xcd;       // 0..31
    int hh = combo >> 3;             // 0..3
    int gg = combo & 7;              // 0..7
    int m0 = tt * 128;
    int h0 = hh * 64;
    int g0 = gg * 32;

    // stage s-slice: [t][m][g] layout -> writes g-contiguous, conflict-free
    {
        int g = tid & 15, m = (tid >> 4) & 1, tb = tid >> 5;
        for (int p = 0; p < 16; p++) {
            int t = tb + p * 8;
            float v = S[((size_t)(m0 + t) * 2 + m) * 256 + g0 + g];
            if (relu_s) v = fmaxf(v, 0.f);
            sl[(t * 2 + m) * 16 + g] = v;
        }
        int g2 = g + 16;   // second 16-g half
        for (int p = 0; p < 16; p++) {
            int t = tb + p * 8;
            float v = S[((size_t)(m0 + t) * 2 + m) * 256 + g0 + g2];
            if (relu_s) v = fmaxf(v, 0.f);
            // NOTE: sl index uses g2-16+... no: sl is [t][m][32]? keep 16KB:
            // sl holds ALL 32 g of this block: [t][m][g 0..31] = 32KB too big.
            // -> store as two 16-g planes is wrong; instead sl is [t][m][16]
            // per HALF and we restage between halves?  No: keep full 32 g by
            // packing g2 into the m-interleave: see layout note below.
            (void)v; (void)g2;
            break;
        }
    }
    // LAYOUT RESOLUTION: sl must hold 32 g per t,m = 128*2*32*4B = 32KB (>16).
    // Instead: sl[t][m][16] holds one 16-g HALF; restage between halves
    // (g-pairs 0..7 use half 0, 8..15 use half 1).  Restage cost: 2 coalesced
    // passes, outside the hot k-loop.
    __syncthreads();   // sl half-0 writes drained (ds) before any read;
                       // no glds outstanding yet so this drain is free.

    int wm = wave >> 1, wn = wave & 1;
    int lrsub = lane >> 3, kcl = lane & 7;
    int kof = (kcl ^ lrsub) * 8;     // row&7 == lrsub for all staged rows

    const u16* gAb = Eb + (size_t)(m0 + wave * 32 + lrsub) * 512 + kof;
    const u16* gBb = Bt + ((size_t)g0 * 256 + h0 + wave * 16 + lrsub) * 512 + kof;

    int arb = wm * 64 + (lane & 15);
    int brb = wn * 32 + (lane & 15);
    int axr = arb & 7, bxr = brb & 7;
    int cl0 = lane >> 4;

    floatx4 yreg[2][4][2];
    #pragma unroll
    for (int m = 0; m < 2; m++)
        #pragma unroll
        for (int r = 0; r < 4; r++)
            #pragma unroll
            for (int c = 0; c < 2; c++)
                #pragma unroll
                for (int q = 0; q < 4; q++) yreg[m][r][c][q] = 0.f;

    // ---- prologue: stage B(gp=0,ks=0) into Bs[0] (4 glds outstanding) ----
    #pragma unroll
    for (int j = 0; j < 2; j++) glds16(gBb + j * 4096, &Bs[0][0][wave * 1024 + j * 512]);
    #pragma unroll
    for (int j = 0; j < 2; j++) glds16(gBb + 131072 + j * 4096, &Bs[0][1][wave * 1024 + j * 512]);

    #pragma unroll 1
    for (int gp = 0; gp < 16; gp++) {
        // restage sl at half boundaries (gp==8): ds-only, no vmcnt touch.
        if (gp == 8) {
            __syncthreads();   // prior apply reads of sl complete
            int g = tid & 15, m = (tid >> 4) & 1, tb = tid >> 5;
            for (int p = 0; p < 16; p++) {
                int t = tb + p * 8;
                float v = S[((size_t)(m0 + t) * 2 + m) * 256 + g0 + 16 + g];
                if (relu_s) v = fmaxf(v, 0.f);
                sl[(t * 2 + m) * 16 + g] = v;
            }
            // NOTE: these S global loads DO bump vmcnt; they are issued and
            // consumed here (compiler waits for them before ds_write), which
            // also drains the in-flight B-next once at this single boundary.
            // One drain per kernel-half is acceptable (vs every gp in r6).
            __syncthreads();
        }
        floatx4 acc[2][4][2];
        #pragma unroll
        for (int u = 0; u < 2; u++)
            #pragma unroll
            for (int r = 0; r < 4; r++)
                #pragma unroll
                for (int c = 0; c < 2; c++)
                    #pragma unroll
                    for (int q = 0; q < 4; q++) acc[u][r][c][q] = 0.f;

        #pragma unroll
        for (int ks = 0; ks < 8; ++ks) {
            const int cb = ks & 1;          // compute buffer (compile-time)
            const int nb = cb ^ 1;          // stage buffer
            // A-current (single-buffered; prev step's end-barrier protects As)
            #pragma unroll
            for (int j = 0; j < 4; j++)
                glds16(gAb + j * 4096 + ks * 64, &As[wave * 2048 + j * 512]);
            // B-next (wraps harmlessly at the very end; drained below)
            {
                const int nk = ((ks + 1) & 7) * 64;
                const int ngp = (ks == 7) ? ((gp + 1) & 15) : gp;
                const size_t ng = (size_t)(2 * ngp) * 131072;
                #pragma unroll
                for (int j = 0; j < 2; j++)
                    glds16(gBb + ng + j * 4096 + nk, &Bs[nb][0][wave * 1024 + j * 512]);
                #pragma unroll
                for (int j = 0; j < 2; j++)
                    glds16(gBb + ng + 131072 + j * 4096 + nk, &Bs[nb][1][wave * 1024 + j * 512]);
            }
            // wait B-cur + A-cur; leave the 4 B-next in flight.
            asm volatile("s_waitcnt vmcnt(4)" ::: "memory");
            __builtin_amdgcn_s_barrier();
            __builtin_amdgcn_sched_barrier(0);
            #pragma unroll
            for (int s = 0; s < 2; s++) {
                shortx8 af[4], bf[2][2];
                int ac = ((s * 4 + cl0) ^ axr) * 8;
                int bc = ((s * 4 + cl0) ^ bxr) * 8;
                #pragma unroll
                for (int r = 0; r < 4; r++)
                    af[r] = *(const shortx8*)(&As[(arb + r * 16) * 64 + ac]);
                #pragma unroll
                for (int u = 0; u < 2; u++)
                    #pragma unroll
                    for (int c = 0; c < 2; c++)
                        bf[u][c] = *(const shortx8*)(&Bs[cb][u][(brb + c * 16) * 64 + bc]);
                #pragma unroll
                for (int r = 0; r < 4; r++)
                    #pragma unroll
                    for (int u = 0; u < 2; u++)
                        #pragma unroll
                        for (int c = 0; c < 2; c++)
                            acc[u][r][c] = __builtin_amdgcn_mfma_f32_16x16x32_bf16(af[r], bf[u][c], acc[u][r][c], 0, 0, 0);
            }
            __builtin_amdgcn_sched_barrier(0);
            __builtin_amdgcn_s_barrier();
        }

        // y += s * W-tile for both gi of the pair.  sl reads: lanes 0..15
        // same addr (broadcast), ds-only -> no vmcnt interaction.
        #pragma unroll
        for (int u = 0; u < 2; u++) {
            int gl = (2 * gp + u) & 15;    // g index within current 16-g half
            #pragma unroll
            for (int m = 0; m < 2; m++)
                #pragma unroll
                for (int r = 0; r < 4; r++)
                    #pragma unroll
                    for (int q = 0; q < 4; q++) {
                        int t = wm * 64 + cl0 * 4 + r * 16 + q;
                        float sv = sl[(t * 2 + m) * 16 + gl];
                        #pragma unroll
                        for (int c = 0; c < 2; c++)
                            yreg[m][r][c][q] += sv * acc[u][r][c][q];
                    }
        }
    }

    // drain the wrap-stage loads before LDS reuse / endpgm
    asm volatile("s_waitcnt vmcnt(0)" ::: "memory");

    // atomic epilogue into Y[t][m][h]
    int l16 = lane & 15;
    #pragma unroll
    for (int m = 0; m < 2; m++)
        #pragma unroll
        for (int r = 0; r < 4; r++)
            #pragma unroll
            for (int c = 0; c < 2; c++)
                #pragma unroll
                for (int q = 0; q < 4; q++) {
                    int t = m0 + wm * 64 + cl0 * 4 + r * 16 + q;
                    int h = h0 + wn * 32 + c * 16 + l16;
                    atomicAdd(&Y[((size_t)t * 2 + m) * 256 + h], yreg[m][r][c][q]);
                }
}

// ---------- final: out[(b*2+m)*64+n][h] = relu(Y2[t][m][h]) ----------
__global__ __launch_bounds__(256) void final_out(const float* __restrict__ Y,
                                                 float* __restrict__ out) {
    int t = blockIdx.x, h = threadIdx.x;
    int b = t >> 6, n = t & 63;
    #pragma unroll
    for (int m = 0; m < 2; m++)
        out[((size_t)((b * 2 + m) * 64) + n) * 256 + h] =
            fmaxf(Y[((size_t)t * 2 + m) * 256 + h], 0.f);
}

// ---------- host ----------
extern "C" void kernel_launch(void* const* d_in, const int* in_sizes, int n_in,
                              void* d_out, int out_size, void* d_ws, size_t ws_size,
                              hipStream_t stream) {
    const float* enc = (const float*)d_in[0];
    const float* mu  = (const float*)d_in[1];
    const float* sg  = (const float*)d_in[2];
    const float* f1w = (const float*)d_in[3];
    const float* f1b = (const float*)d_in[4];
    const float* f2w = (const float*)d_in[5];
    const float* f2b = (const float*)d_in[6];
    const float* eps = (const float*)d_in[7];
    float* out = (float*)d_out;

    size_t off = 0;
    auto alloc = [&](size_t b) -> char* {
        char* p = (char*)d_ws + off; off += (b + 255) & ~(size_t)255; return p;
    };
    u16*   Eb    = (u16*)  alloc((size_t)2048 * 512 * 2);
    float* P     = (float*)alloc((size_t)2048 * 1024 * 4);
    float* slots = (float*)alloc((size_t)2048 * 512 * 4);
    float* Y1    = (float*)alloc((size_t)2048 * 512 * 4);
    float* Y2    = (float*)alloc((size_t)2048 * 512 * 4);
    u16*   Bsm   = (u16*)  alloc((size_t)1024 * 512 * 2);
    u16*   Bt    = (u16*)  alloc((size_t)65536 * 512 * 2);

    cvt_bf16_kernel<<<1024, 256, 0, stream>>>(enc, Eb, 2048 * 512);
    build_bsmall_t<<<dim3(16, 8, 4), 256, 0, stream>>>(mu, sg, f1b, f2b, Bsm);
    gemm_small<<<128, 256, 0, stream>>>(Eb, Bsm, P, 1024, 512, 4, 0);
    slots_init<<<2048, 256, 0, stream>>>(P, eps, slots, Y1, Y2);

    // layer 1
    cvt_transpose<<<dim3(2048, 8), 256, 0, stream>>>(f1w, Bt);
    fused_mlp<<<512, 256, 0, stream>>>(Eb, Bt, slots, Y1, 0);

    // layer 2 (relu folded into s-loader)
    cvt_transpose<<<dim3(2048, 8), 256, 0, stream>>>(f2w, Bt);
    fused_mlp<<<512, 256, 0, stream>>>(Eb, Bt, Y1, Y2, 1);

    final_out<<<2048, 256, 0, stream>>>(Y2, out);
}

// Round 8
// 634.127 us; speedup vs baseline: 1.1375x; 1.1375x over previous
//
#include <hip/hip_runtime.h>
#include <hip/hip_bf16.h>

typedef unsigned short u16;
typedef __attribute__((ext_vector_type(8))) short shortx8;
typedef __attribute__((ext_vector_type(4))) float floatx4;

// ---------- helpers ----------
__device__ __forceinline__ float bf2f(u16 u) {
    union { unsigned int ui; float f; } x; x.ui = ((unsigned int)u) << 16; return x.f;
}
__device__ __forceinline__ u16 f2b(float f) {
    union { float f; unsigned int u; } x; x.f = f;
    unsigned int r = (x.u + 0x7fffu + ((x.u >> 16) & 1u)) >> 16;   // RNE
    return (u16)r;
}
__device__ __forceinline__ void glds16(const void* g, void* l) {
    __builtin_amdgcn_global_load_lds((const __attribute__((address_space(1))) void*)g,
                                     (__attribute__((address_space(3))) void*)l, 16, 0, 0);
}

// ---------- fp32 -> bf16 elementwise (encodings) ----------
__global__ __launch_bounds__(256) void cvt_bf16_kernel(const float* __restrict__ src,
                                                       u16* __restrict__ dst, int n) {
    int i = (blockIdx.x * 256 + threadIdx.x) * 4;
    if (i + 3 < n) {
        float4 v = *(const float4*)&src[i];
        ushort4 o; o.x = f2b(v.x); o.y = f2b(v.y); o.z = f2b(v.z); o.w = f2b(v.w);
        *(ushort4*)&dst[i] = o;
    }
}

// ---------- build Bsmall' [1024][512] bf16 via coalesced LDS transpose ----------
__global__ __launch_bounds__(256) void build_bsmall_t(const float* __restrict__ mu,
                                                      const float* __restrict__ sg,
                                                      const float* __restrict__ b1,
                                                      const float* __restrict__ b2,
                                                      u16* __restrict__ Bs) {
    __shared__ float t[32][33];
    const float* src;
    int z = blockIdx.z;
    if (z == 0) src = mu; else if (z == 1) src = sg; else if (z == 2) src = b1; else src = b2;
    int k0 = blockIdx.x * 32, c0 = blockIdx.y * 32;
    int r = threadIdx.x >> 3, c4 = (threadIdx.x & 7) * 4;
    float4 v = *(const float4*)&src[(size_t)(k0 + r) * 256 + c0 + c4];
    t[r][c4] = v.x; t[r][c4 + 1] = v.y; t[r][c4 + 2] = v.z; t[r][c4 + 3] = v.w;
    __syncthreads();
    ushort4 o;
    o.x = f2b(t[c4 + 0][r]); o.y = f2b(t[c4 + 1][r]);
    o.z = f2b(t[c4 + 2][r]); o.w = f2b(t[c4 + 3][r]);
    *(ushort4*)&Bs[(size_t)(z * 256 + c0 + r) * 512 + k0 + c4] = o;
}

// ---------- fc_w fp32 [512][65536] -> bf16 transposed [65536][512] ----------
// 64k x 32n tile.  Writes 16B/thread (shortx8), 128B-contiguous per 8-thread
// run; reads 128B-coalesced; LDS gather at stride 33 is 2-way aliasing (free).
__global__ __launch_bounds__(256) void cvt_transpose(const float* __restrict__ W,
                                                     u16* __restrict__ Bt) {
    __shared__ float t[64][33];
    int n0 = blockIdx.x * 32, k0 = blockIdx.y * 64;
    int r = threadIdx.x >> 2;          // 0..63 (k-row)
    int c = (threadIdx.x & 3) * 8;     // 0,8,16,24 (n-col)
    float4 v0 = *(const float4*)&W[(size_t)(k0 + r) * 65536 + n0 + c];
    float4 v1 = *(const float4*)&W[(size_t)(k0 + r) * 65536 + n0 + c + 4];
    t[r][c + 0] = v0.x; t[r][c + 1] = v0.y; t[r][c + 2] = v0.z; t[r][c + 3] = v0.w;
    t[r][c + 4] = v1.x; t[r][c + 5] = v1.y; t[r][c + 6] = v1.z; t[r][c + 7] = v1.w;
    __syncthreads();
    int nr = threadIdx.x >> 3;         // 0..31 (n-row)
    int kk = (threadIdx.x & 7) * 8;    // 0..56 (k)
    shortx8 o;
    #pragma unroll
    for (int i = 0; i < 8; i++) o[i] = (short)f2b(t[kk + i][nr]);
    *(shortx8*)&Bt[(size_t)(n0 + nr) * 512 + k0 + kk] = o;
}

// ---------- slots + Y1/Y2 bias init (fused; reads P once) ----------
__global__ __launch_bounds__(256) void slots_init(const float* __restrict__ P,
                                                  const float* __restrict__ eps,
                                                  float* __restrict__ slots,
                                                  float* __restrict__ Y1,
                                                  float* __restrict__ Y2) {
    int t = blockIdx.x, d = threadIdx.x;
    float mu = P[(size_t)t * 1024 + d];
    float sg = expf(0.5f * P[(size_t)t * 1024 + 256 + d]);
    float b1 = P[(size_t)t * 1024 + 512 + d];
    float b2 = P[(size_t)t * 1024 + 768 + d];
    Y1[((size_t)t * 2 + 0) * 256 + d] = b1;
    Y1[((size_t)t * 2 + 1) * 256 + d] = b1;
    Y2[((size_t)t * 2 + 0) * 256 + d] = b2;
    Y2[((size_t)t * 2 + 1) * 256 + d] = b2;
    int b = t >> 6, n = t & 63;
    #pragma unroll
    for (int m = 0; m < 2; m++) {
        float e = eps[(size_t)(((b * 2 + m) * 64) + n) * 256 + d];
        slots[(size_t)t * 512 + m * 256 + d] = mu + sg * e;
    }
}

// ---------- small MFMA GEMM (fp32 out): P = Eb * Bsm^T ----------
__global__ __launch_bounds__(256, 2) void gemm_small(const u16* __restrict__ A,
                                                     const u16* __restrict__ B,
                                                     float* __restrict__ C,
                                                     int N, int K,
                                                     int nbx_l2, int bypx_l2) {
    __shared__ __align__(16) u16 As[128 * 64];
    __shared__ __align__(16) u16 Bs[128 * 64];
    int tid = threadIdx.x;
    int wave = tid >> 6, lane = tid & 63;

    int id = blockIdx.x;
    int xcd = id & 7, sq = id >> 3;
    int by = (xcd << bypx_l2) + (sq >> nbx_l2);
    int bx = sq & ((1 << nbx_l2) - 1);
    int m0 = bx * 128, n0 = by * 128;
    int wm = wave >> 1, wn = wave & 1;

    floatx4 acc[4][4];
    #pragma unroll
    for (int r = 0; r < 4; r++)
        #pragma unroll
        for (int c = 0; c < 4; c++)
            #pragma unroll
            for (int q = 0; q < 4; q++) acc[r][c][q] = 0.f;

    int lrsub = lane >> 3, kcl = lane & 7;
    const u16* gA[4]; const u16* gB[4]; u16* lA[4]; u16* lB[4];
    #pragma unroll
    for (int j = 0; j < 4; j++) {
        int r0 = (wave * 4 + j) * 8;
        int row = r0 + lrsub;
        int kof = (kcl ^ (row & 7)) * 8;
        gA[j] = A + (size_t)(m0 + row) * K + kof;
        gB[j] = B + (size_t)(n0 + row) * K + kof;
        lA[j] = As + r0 * 64;
        lB[j] = Bs + r0 * 64;
    }

    int arb = wm * 64 + (lane & 15);
    int brb = wn * 64 + (lane & 15);
    int axr = arb & 7, bxr = brb & 7;
    int cl0 = lane >> 4;

    for (int k0 = 0; k0 < K; k0 += 64) {
        #pragma unroll
        for (int j = 0; j < 4; j++) glds16(gA[j] + k0, lA[j]);
        #pragma unroll
        for (int j = 0; j < 4; j++) glds16(gB[j] + k0, lB[j]);
        __syncthreads();
        #pragma unroll
        for (int s = 0; s < 2; s++) {
            shortx8 af[4], bf[4];
            int ac = ((s * 4 + cl0) ^ axr) * 8;
            int bc = ((s * 4 + cl0) ^ bxr) * 8;
            #pragma unroll
            for (int r = 0; r < 4; r++) af[r] = *(const shortx8*)(As + (arb + r * 16) * 64 + ac);
            #pragma unroll
            for (int c = 0; c < 4; c++) bf[c] = *(const shortx8*)(Bs + (brb + c * 16) * 64 + bc);
            #pragma unroll
            for (int r = 0; r < 4; r++)
                #pragma unroll
                for (int c = 0; c < 4; c++)
                    acc[r][c] = __builtin_amdgcn_mfma_f32_16x16x32_bf16(af[r], bf[c], acc[r][c], 0, 0, 0);
        }
        __syncthreads();
    }

    int crow0 = m0 + wm * 64 + (lane >> 4) * 4;
    int ccol  = n0 + wn * 64 + (lane & 15);
    #pragma unroll
    for (int r = 0; r < 4; r++)
        #pragma unroll
        for (int c = 0; c < 4; c++)
            #pragma unroll
            for (int q = 0; q < 4; q++)
                C[(size_t)(crow0 + r * 16 + q) * N + ccol + c * 16] = acc[r][c][q];
}

// ---------- fused mixture-GEMM + apply ----------
// Block = (token-tile 128, h-tile 64, g-group 32), 512 blocks = 2/CU exact.
// g in PAIRS (G_INNER=2, F=4.0 fragment reuse).  32 g's in two 16-g halves
// with sl restaged between halves; LDS = 48KB (2 blk/CU).
//
// PROVEN STATE (round 5): 170us, MfmaUtil 34.6, FETCH 45MB, WRITE 33MB.
// DO NOT re-pipeline this kernel.  Evidence:
//  - r2: dbuf + drain-0 per step  -> neutral (255us vs 232 pre-G_INNER)
//  - r6: full dbuf + vmcnt(8), sl->global apply -> 209us, apply drained
//        the prefetch every gp (vmcnt is one in-order counter)
//  - r7: B-dbuf + vmcnt(4), sl in LDS -> 217us, FETCH 44->140MB: deeper
//        prefetch de-synced the 16 tt-siblings sharing each B-panel and
//        killed L2 reuse.  The implicit 2-barrier structure + 2 resident
//        blocks (m114 wave-overlap) IS the local optimum here.
// REGISTER ECONOMICS (rounds 0-3): only (256,2) avoids spilling ~200-reg
// live state.  (256,4)->VGPR64/+650MB scratch; (256,3)->VGPR84/+170MB.
// Known residual: 4.06M LDS bank conflicts = sl staging writes ([g][m][t],
// 16 g-lanes hit one bank); worth <=4%, fix only in isolation.
__global__ __launch_bounds__(256, 2) void fused_mlp(const u16* __restrict__ Eb,
                                                    const u16* __restrict__ Bt,
                                                    const float* __restrict__ S,
                                                    float* __restrict__ Y,
                                                    int relu_s) {
    __shared__ __align__(16) u16 As[128 * 64];      // 16 KB
    __shared__ __align__(16) u16 Bs[2][64 * 64];    // 16 KB
    __shared__ float sl[16 * 2 * 128];              // [g-local][m][t] 16 KB
    int tid = threadIdx.x;
    int wave = tid >> 6, lane = tid & 63;

    // decode with XCD-affinity on (hh,gg): same-B blocks share an XCD and are
    // consecutive in dispatch order (L2 temporal locality).
    int id = blockIdx.x;
    int xcd = id & 7;
    int rest = id >> 3;
    int tt = rest & 15;              // 0..15
    int chi = rest >> 4;             // 0..3
    int combo = chi * 8 + xcd;       // 0..31
    int hh = combo >> 3;             // 0..3
    int gg = combo & 7;              // 0..7
    int m0 = tt * 128;
    int h0 = hh * 64;
    int g0 = gg * 32;

    int wm = wave >> 1, wn = wave & 1;
    int lrsub = lane >> 3, kcl = lane & 7;
    int kof = (kcl ^ lrsub) * 8;     // row&7 == lrsub for all staged rows

    // single base pointers; j-steps are uniform immediates (j*8 rows * 512 k)
    const u16* gAb = Eb + (size_t)(m0 + wave * 32 + lrsub) * 512 + kof;
    const u16* gBb = Bt + ((size_t)g0 * 256 + h0 + wave * 16 + lrsub) * 512 + kof;
    u16* lAb = As + wave * 2048;            // + j*512
    u16* lB0 = &Bs[0][wave * 1024];         // + j*512
    u16* lB1 = &Bs[1][wave * 1024];

    int arb = wm * 64 + (lane & 15);
    int brb = wn * 32 + (lane & 15);
    int axr = arb & 7, bxr = brb & 7;
    int cl0 = lane >> 4;

    floatx4 yreg[2][4][2];
    #pragma unroll
    for (int m = 0; m < 2; m++)
        #pragma unroll
        for (int r = 0; r < 4; r++)
            #pragma unroll
            for (int c = 0; c < 2; c++)
                #pragma unroll
                for (int q = 0; q < 4; q++) yreg[m][r][c][q] = 0.f;

    #pragma unroll 1
    for (int half = 0; half < 2; half++) {
        // stage s-slice for this 16-g half (coalesced 64B runs in g).
        // __syncthreads: previous half's apply-reads of sl are complete.
        __syncthreads();
        {
            int g = tid & 15, m = (tid >> 4) & 1, tb = tid >> 5;
            for (int p = 0; p < 16; p++) {
                int t = tb + p * 8;
                float v = S[((size_t)(m0 + t) * 2 + m) * 256 + g0 + half * 16 + g];
                if (relu_s) v = fmaxf(v, 0.f);
                sl[(g * 2 + m) * 128 + t] = v;
            }
        }
        // NOTE: no barrier needed here -- the first k-step's __syncthreads
        // below orders these ds_writes before any sl read (sl is only read
        // in the apply, which is after at least one __syncthreads).

        #pragma unroll 1
        for (int gp = 0; gp < 8; gp++) {
            size_t gof0 = (size_t)(half * 16 + 2 * gp) * 131072;   // g-row offset
            size_t gof1 = gof0 + 131072;
            floatx4 acc[2][4][2];
            #pragma unroll
            for (int u = 0; u < 2; u++)
                #pragma unroll
                for (int r = 0; r < 4; r++)
                    #pragma unroll
                    for (int c = 0; c < 2; c++)
                        #pragma unroll
                        for (int q = 0; q < 4; q++) acc[u][r][c][q] = 0.f;

            for (int k0 = 0; k0 < 512; k0 += 64) {
                #pragma unroll
                for (int j = 0; j < 4; j++) glds16(gAb + j * 4096 + k0, lAb + j * 512);
                #pragma unroll
                for (int j = 0; j < 2; j++) glds16(gBb + gof0 + j * 4096 + k0, lB0 + j * 512);
                #pragma unroll
                for (int j = 0; j < 2; j++) glds16(gBb + gof1 + j * 4096 + k0, lB1 + j * 512);
                __syncthreads();
                #pragma unroll
                for (int s = 0; s < 2; s++) {
                    shortx8 af[4], bf[2][2];
                    int ac = ((s * 4 + cl0) ^ axr) * 8;
                    int bc = ((s * 4 + cl0) ^ bxr) * 8;
                    #pragma unroll
                    for (int r = 0; r < 4; r++) af[r] = *(const shortx8*)(As + (arb + r * 16) * 64 + ac);
                    #pragma unroll
                    for (int u = 0; u < 2; u++)
                        #pragma unroll
                        for (int c = 0; c < 2; c++)
                            bf[u][c] = *(const shortx8*)(&Bs[u][(brb + c * 16) * 64 + bc]);
                    #pragma unroll
                    for (int r = 0; r < 4; r++)
                        #pragma unroll
                        for (int u = 0; u < 2; u++)
                            #pragma unroll
                            for (int c = 0; c < 2; c++)
                                acc[u][r][c] = __builtin_amdgcn_mfma_f32_16x16x32_bf16(af[r], bf[u][c], acc[u][r][c], 0, 0, 0);
                }
                __syncthreads();
            }

            // y += s * W-tile for both gi of the pair (sl reads wave-broadcast)
            #pragma unroll
            for (int u = 0; u < 2; u++) {
                int gi = 2 * gp + u;   // local g index within the half
                #pragma unroll
                for (int m = 0; m < 2; m++) {
                    float4 sq[4];
                    #pragma unroll
                    for (int r = 0; r < 4; r++)
                        sq[r] = *(const float4*)&sl[(gi * 2 + m) * 128 + wm * 64 + cl0 * 4 + r * 16];
                    #pragma unroll
                    for (int r = 0; r < 4; r++)
                        #pragma unroll
                        for (int c = 0; c < 2; c++)
                            #pragma unroll
                            for (int q = 0; q < 4; q++)
                                yreg[m][r][c][q] += ((const float*)&sq[r])[q] * acc[u][r][c][q];
                }
            }
        }
    }

    // atomic epilogue into Y[t][m][h]
    int l16 = lane & 15;
    #pragma unroll
    for (int m = 0; m < 2; m++)
        #pragma unroll
        for (int r = 0; r < 4; r++)
            #pragma unroll
            for (int c = 0; c < 2; c++)
                #pragma unroll
                for (int q = 0; q < 4; q++) {
                    int t = m0 + wm * 64 + cl0 * 4 + r * 16 + q;
                    int h = h0 + wn * 32 + c * 16 + l16;
                    atomicAdd(&Y[((size_t)t * 2 + m) * 256 + h], yreg[m][r][c][q]);
                }
}

// ---------- final: out[(b*2+m)*64+n][h] = relu(Y2[t][m][h]) ----------
__global__ __launch_bounds__(256) void final_out(const float* __restrict__ Y,
                                                 float* __restrict__ out) {
    int t = blockIdx.x, h = threadIdx.x;
    int b = t >> 6, n = t & 63;
    #pragma unroll
    for (int m = 0; m < 2; m++)
        out[((size_t)((b * 2 + m) * 64) + n) * 256 + h] =
            fmaxf(Y[((size_t)t * 2 + m) * 256 + h], 0.f);
}

// ---------- host ----------
extern "C" void kernel_launch(void* const* d_in, const int* in_sizes, int n_in,
                              void* d_out, int out_size, void* d_ws, size_t ws_size,
                              hipStream_t stream) {
    const float* enc = (const float*)d_in[0];
    const float* mu  = (const float*)d_in[1];
    const float* sg  = (const float*)d_in[2];
    const float* f1w = (const float*)d_in[3];
    const float* f1b = (const float*)d_in[4];
    const float* f2w = (const float*)d_in[5];
    const float* f2b = (const float*)d_in[6];
    const float* eps = (const float*)d_in[7];
    float* out = (float*)d_out;

    size_t off = 0;
    auto alloc = [&](size_t b) -> char* {
        char* p = (char*)d_ws + off; off += (b + 255) & ~(size_t)255; return p;
    };
    u16*   Eb    = (u16*)  alloc((size_t)2048 * 512 * 2);
    float* P     = (float*)alloc((size_t)2048 * 1024 * 4);
    float* slots = (float*)alloc((size_t)2048 * 512 * 4);
    float* Y1    = (float*)alloc((size_t)2048 * 512 * 4);
    float* Y2    = (float*)alloc((size_t)2048 * 512 * 4);
    u16*   Bsm   = (u16*)  alloc((size_t)1024 * 512 * 2);
    u16*   Bt    = (u16*)  alloc((size_t)65536 * 512 * 2);

    cvt_bf16_kernel<<<1024, 256, 0, stream>>>(enc, Eb, 2048 * 512);
    build_bsmall_t<<<dim3(16, 8, 4), 256, 0, stream>>>(mu, sg, f1b, f2b, Bsm);
    gemm_small<<<128, 256, 0, stream>>>(Eb, Bsm, P, 1024, 512, 4, 0);
    slots_init<<<2048, 256, 0, stream>>>(P, eps, slots, Y1, Y2);

    // layer 1
    cvt_transpose<<<dim3(2048, 8), 256, 0, stream>>>(f1w, Bt);
    fused_mlp<<<512, 256, 0, stream>>>(Eb, Bt, slots, Y1, 0);

    // layer 2 (relu folded into s-loader)
    cvt_transpose<<<dim3(2048, 8), 256, 0, stream>>>(f2w, Bt);
    fused_mlp<<<512, 256, 0, stream>>>(Eb, Bt, Y1, Y2, 1);

    final_out<<<2048, 256, 0, stream>>>(Y2, out);
}